// Round 4
// baseline (677.515 us; speedup 1.0000x reference)
//
#include <hip/hip_runtime.h>
#include <hip/hip_bf16.h>

typedef __hip_bfloat16 bf16;
typedef __attribute__((ext_vector_type(8))) short bf16x8;    // 8 bf16 = 4 VGPRs
typedef __attribute__((ext_vector_type(4))) float f32x4;
typedef __attribute__((ext_vector_type(16))) float f32x16;   // 32x32 acc
typedef __attribute__((ext_vector_type(4))) int int4v;

#define AS1 __attribute__((address_space(1)))
#define AS3 __attribute__((address_space(3)))

#define MDIM 8192   // B*S
#define NDIM 4096   // D_OUT
#define KDIM 4096   // D_IN
#define SCALING 2.0f

#define FOLD_BLOCKS (NDIM * KDIM / 8 / 256)   // 8192
#define CONV_BLOCKS (MDIM * KDIM / 8 / 256)   // 16384

// ---------------------------------------------------------------------------
// prep: one launch doing both
//   blocks [0, 8192):      Weff = W + SCALING*(lora_B@lora_A) + mask?delta  -> bf16
//   blocks [8192, 24576):  Xb = bf16(X)
// Both memory-bound; ~435 MB total traffic.
// ---------------------------------------------------------------------------
__global__ __launch_bounds__(256) void prep(
    const float* __restrict__ W, const float* __restrict__ lA,
    const float* __restrict__ lB, const float* __restrict__ delta,
    const int* __restrict__ mask, const float* __restrict__ X,
    bf16* __restrict__ Weff, bf16* __restrict__ Xb)
{
    if (blockIdx.x < FOLD_BLOCKS) {
        int idx = blockIdx.x * 256 + threadIdx.x;
        int o   = idx >> 9;                     // 512 threads per row of 4096
        int d0  = (idx & 511) << 3;
        size_t base = (size_t)o * KDIM + d0;

        float Bo[16];
#pragma unroll
        for (int r = 0; r < 16; ++r) Bo[r] = lB[o * 16 + r];

        f32x4 wa = *(const f32x4*)(W + base);
        f32x4 wb = *(const f32x4*)(W + base + 4);
        f32x4 da = *(const f32x4*)(delta + base);
        f32x4 db = *(const f32x4*)(delta + base + 4);

        int mk[8];
        *(int4v*)(mk)     = *(const int4v*)(mask + base);
        *(int4v*)(mk + 4) = *(const int4v*)(mask + base + 4);

        float lor[8] = {0.f, 0.f, 0.f, 0.f, 0.f, 0.f, 0.f, 0.f};
#pragma unroll
        for (int r = 0; r < 16; ++r) {
            f32x4 aa = *(const f32x4*)(lA + (size_t)r * KDIM + d0);
            f32x4 ab = *(const f32x4*)(lA + (size_t)r * KDIM + d0 + 4);
#pragma unroll
            for (int e = 0; e < 4; ++e) {
                lor[e]     += Bo[r] * aa[e];
                lor[e + 4] += Bo[r] * ab[e];
            }
        }

        int4v ov4;
        bf16* ov = (bf16*)&ov4;
#pragma unroll
        for (int e = 0; e < 8; ++e) {
            float w = (e < 4) ? wa[e] : wb[e - 4];
            float d = (e < 4) ? da[e] : db[e - 4];
            float a = w + SCALING * lor[e];
            if (mk[e]) a += d;
            ov[e] = __float2bfloat16(a);
        }
        *(int4v*)(Weff + base) = ov4;
    } else {
        size_t i = ((size_t)(blockIdx.x - FOLD_BLOCKS) * 256 + threadIdx.x) * 8;
        f32x4 a = *(const f32x4*)(X + i);
        f32x4 b = *(const f32x4*)(X + i + 4);
        int4v ov4;
        bf16* ov = (bf16*)&ov4;
#pragma unroll
        for (int e = 0; e < 4; ++e) {
            ov[e]     = __float2bfloat16(a[e]);
            ov[e + 4] = __float2bfloat16(b[e]);
        }
        *(int4v*)(Xb + i) = ov4;
    }
}

// ---------------------------------------------------------------------------
// GEMM (bf16 x bf16 -> fp32): out[m][n] = sum_k Xb[m][k]*Wt[n][k] + bias[n]
// 128x128 tile, BK=64, 2x2 waves, each wave 2x2 of mfma_f32_32x32x16_bf16.
// vs round-3 16x16x32: half the MFMA issue slots, 15% higher MFMA rate,
// same LDS traffic, same 64-reg accumulator.
// global_load_lds width=16; XOR swizzle on 16B chunks -> 0 bank conflicts.
// ---------------------------------------------------------------------------
__global__ __launch_bounds__(256, 4) void gemm_bf16(
    const bf16* __restrict__ X, const bf16* __restrict__ Wt,
    const float* __restrict__ bias, float* __restrict__ out)
{
    __shared__ bf16 As[128 * 64];   // 16 KB
    __shared__ bf16 Bs[128 * 64];   // 16 KB

    const int tid  = threadIdx.x;
    const int lane = tid & 63;
    const int wave = tid >> 6;
    const int wm   = wave & 1;       // 2x2 wave grid, each wave owns 64x64
    const int wn   = wave >> 1;
    const int half = lane >> 5;      // 0/1: k-group within fragment
    const int l32  = lane & 31;

    const int bn = blockIdx.x * 128;
    const int bm = blockIdx.y * 128;
    const int cwave = tid & ~63;

    f32x16 acc[2][2];
#pragma unroll
    for (int i = 0; i < 2; ++i)
#pragma unroll
        for (int j = 0; j < 2; ++j)
#pragma unroll
            for (int r = 0; r < 16; ++r)
                acc[i][j][r] = 0.f;

    for (int kt = 0; kt < KDIM / 64; ++kt) {
        const int k0 = kt * 64;
        if (kt) __syncthreads();
        // Stage A (128x64) and B (128x64): 1024 16B-chunks each, 4/thread.
        // LDS chunk c holds logical (row = c>>3, kc = (c&7) ^ (row&7)).
#pragma unroll
        for (int j = 0; j < 4; ++j) {
            const int c  = j * 256 + tid;
            const int m  = c >> 3;
            const int kc = (c & 7) ^ (m & 7);
            const int cb = j * 256 + cwave;
            __builtin_amdgcn_global_load_lds(
                (const AS1 void*)(X + (size_t)(bm + m) * KDIM + k0 + kc * 8),
                (AS3 void*)(As + cb * 8), 16, 0, 0);
            __builtin_amdgcn_global_load_lds(
                (const AS1 void*)(Wt + (size_t)(bn + m) * KDIM + k0 + kc * 8),
                (AS3 void*)(Bs + cb * 8), 16, 0, 0);
        }
        __syncthreads();

        // 4 K-steps of 16; A-frag: m=lane&31, k=half*8+j (same half-lane
        // k-grouping family as the verified 16x16x32 path; any common k-perm
        // cancels between A and B).
#pragma unroll
        for (int ks = 0; ks < 4; ++ks) {
            const int kcl = ks * 2 + half;      // logical 16B chunk
            bf16x8 af[2], bfr[2];
#pragma unroll
            for (int i = 0; i < 2; ++i) {
                const int m = wm * 64 + i * 32 + l32;
                af[i]  = *(const bf16x8*)(As + m * 64 + (kcl ^ (m & 7)) * 8);
                const int n = wn * 64 + i * 32 + l32;
                bfr[i] = *(const bf16x8*)(Bs + n * 64 + (kcl ^ (n & 7)) * 8);
            }
#pragma unroll
            for (int i = 0; i < 2; ++i)
#pragma unroll
                for (int j = 0; j < 2; ++j)
                    acc[i][j] = __builtin_amdgcn_mfma_f32_32x32x16_bf16(
                        af[i], bfr[j], acc[i][j], 0, 0, 0);
        }
    }

    // C/D (m74/m101-verified): col = lane&31, row = (reg&3)+8*(reg>>2)+4*half
    float bv[2];
#pragma unroll
    for (int j = 0; j < 2; ++j)
        bv[j] = bias[bn + wn * 64 + j * 32 + l32];

#pragma unroll
    for (int i = 0; i < 2; ++i) {
#pragma unroll
        for (int j = 0; j < 2; ++j) {
            const int ng = bn + wn * 64 + j * 32 + l32;
#pragma unroll
            for (int g = 0; g < 4; ++g) {
#pragma unroll
                for (int r = 0; r < 4; ++r) {
                    const int mg = bm + wm * 64 + i * 32 + r + 8 * g + 4 * half;
                    out[(size_t)mg * NDIM + ng] = acc[i][j][4 * g + r] + bv[j];
                }
            }
        }
    }
}

// ---------------------------------------------------------------------------
extern "C" void kernel_launch(void* const* d_in, const int* in_sizes, int n_in,
                              void* d_out, int out_size, void* d_ws, size_t ws_size,
                              hipStream_t stream)
{
    const float* x     = (const float*)d_in[0];
    const float* W     = (const float*)d_in[1];
    const float* b     = (const float*)d_in[2];
    const float* lA    = (const float*)d_in[3];
    const float* lB    = (const float*)d_in[4];
    const float* delta = (const float*)d_in[5];
    const int*   mask  = (const int*)d_in[6];
    float* out = (float*)d_out;

    bf16* Weff = (bf16*)d_ws;                                     // 33.5 MB
    bf16* Xb   = (bf16*)((char*)d_ws + (size_t)NDIM * KDIM * 2);  // 67 MB

    prep<<<dim3(FOLD_BLOCKS + CONV_BLOCKS), 256, 0, stream>>>(
        W, lA, lB, delta, mask, x, Weff, Xb);

    gemm_bf16<<<dim3(NDIM / 128, MDIM / 128), 256, 0, stream>>>(
        Xb, Weff, b, out);
}